// Round 7
// baseline (209.476 us; speedup 1.0000x reference)
//
#include <hip/hip_runtime.h>

#define BATCH 32
#define NDIM 512
#define LNUM 8
#define KDIM 8

// per-batch workspace layout (float offsets)
#define WS_PM     0        // int[512]  posmap: node -> pos in S, or -1
#define WS_S      512      // int[64]   S (padded with 0 beyond s)
#define WS_SCNT   576      // int[1]    |S|
#define WS_ACT    640      // float[512] active mask
#define WS_W      1152     // float[64*64]
#define WS_B2     5248     // float[64*64] B2 = W A_SS W^T
#define WS_C2     9344     // float[64*64] C2 = W^T D_SS W
#define WS_STRIDE 78976

#define LSTR 65
typedef float f4 __attribute__((ext_vector_type(4)));

// ---------------------------------------------------------------------------
// k_small: per-batch serial chain (32 blocks): setup + W + B2/C2 to ws.
__global__ __launch_bounds__(256) void k_small(
    const float* __restrict__ A, const float* __restrict__ O,
    const int* __restrict__ indices, const int* __restrict__ wavelet,
    float* __restrict__ ws)
{
    const int b = blockIdx.x;
    const int tid = threadIdx.x;
    float* base = ws + (size_t)b * WS_STRIDE;

    __shared__ float Wl[64*LSTR];
    __shared__ float P1[64*LSTR];
    __shared__ float P2[64*LSTR];
    __shared__ float B2l[64*LSTR];
    __shared__ int   pml[NDIM];
    __shared__ float actl[NDIM];
    __shared__ float actS[64];
    __shared__ int   idxsh[64];
    __shared__ int   Ssh[64];
    __shared__ int   prow[KDIM];
    __shared__ float Oall[LNUM*KDIM*KDIM];
    __shared__ int   s_sh;

    for (int t = tid; t < LNUM*KDIM*KDIM; t += 256) {
        int l = t >> 6, k = t & 63;
        Oall[t] = O[((size_t)l*BATCH + b)*(KDIM*KDIM) + k];
    }
    if (tid < 64) idxsh[tid] = indices[b*64 + tid];
    for (int n = tid; n < NDIM; n += 256) { pml[n] = -1; actl[n] = 1.f; }
    __syncthreads();

    if (tid < 64) {
        int n = idxsh[tid];
        bool first = true;
        for (int t = 0; t < tid; ++t) if (idxsh[t] == n) first = false;
        unsigned long long m = __ballot(first);
        int rank = __popcll(m & ((1ull << tid) - 1ull));
        if (first) { pml[n] = rank; Ssh[rank] = n; }
        if (tid == 0) s_sh = (int)__popcll(m);
    }
    if (tid >= 64 && tid < 64 + LNUM) {
        actl[wavelet[b*LNUM + (tid - 64)]] = 0.f;
    }
    __syncthreads();
    const int s = s_sh;
    if (tid < 64 && tid >= s) Ssh[tid] = 0;
    __syncthreads();
    if (tid < 64) actS[tid] = actl[Ssh[tid]];

    {
        int*   g_posmap = (int*)(base + WS_PM);
        int*   g_S      = (int*)(base + WS_S);
        float* g_act    = base + WS_ACT;
        for (int n = tid; n < NDIM; n += 256) { g_posmap[n] = pml[n]; g_act[n] = actl[n]; }
        if (tid < 64) g_S[tid] = Ssh[tid];
        if (tid == 0) ((int*)(base + WS_SCNT))[0] = s;
    }

    // W build
    for (int t = tid; t < 4096; t += 256) {
        int rr = t >> 6, cc = t & 63;
        Wl[rr*LSTR + cc] = (rr == cc && rr < s) ? 1.f : 0.f;
    }
    __syncthreads();
    for (int l = 0; l < LNUM; ++l) {
        if (tid < KDIM) prow[tid] = pml[idxsh[l*KDIM + tid]];
        __syncthreads();
        for (int t = tid; t < KDIM*64; t += 256) {
            int i = t >> 6, c = t & 63;
            float acc = 0.f;
            #pragma unroll
            for (int j = 0; j < KDIM; ++j)
                acc += Oall[l*64 + i*KDIM + j] * Wl[prow[j]*LSTR + c];
            B2l[t] = acc;
        }
        __syncthreads();
        for (int t = tid; t < KDIM*64; t += 256) {
            int i = t >> 6, c = t & 63;
            Wl[prow[i]*LSTR + c] = B2l[t];
        }
        __syncthreads();
    }
    {
        float* g_W = base + WS_W;
        for (int t = tid; t < 4096; t += 256) g_W[t] = Wl[(t>>6)*LSTR + (t&63)];
    }

    // gather A_SS -> P1
    for (int t = tid; t < 4096; t += 256) {
        int n = t >> 6, m = t & 63;
        P1[n*LSTR + m] = A[((size_t)b*NDIM + Ssh[n])*NDIM + Ssh[m]];
    }
    __syncthreads();

    const int w = tid >> 6;
    const int ln = tid & 63;
    float acc[16];

    // T = W * A_SS -> P2
    #pragma unroll
    for (int k = 0; k < 16; ++k) acc[k] = 0.f;
    for (int n = 0; n < 64; ++n) {
        float as = P1[n*LSTR + ln];
        #pragma unroll
        for (int k = 0; k < 16; ++k) acc[k] += Wl[(w*16 + k)*LSTR + n] * as;
    }
    #pragma unroll
    for (int k = 0; k < 16; ++k) P2[(w*16 + k)*LSTR + ln] = acc[k];
    __syncthreads();

    // B2 = T * W^T
    #pragma unroll
    for (int k = 0; k < 16; ++k) acc[k] = 0.f;
    for (int m = 0; m < 64; ++m) {
        float wv = Wl[ln*LSTR + m];
        #pragma unroll
        for (int k = 0; k < 16; ++k) acc[k] += P2[(w*16 + k)*LSTR + m] * wv;
    }
    #pragma unroll
    for (int k = 0; k < 16; ++k) B2l[(w*16 + k)*LSTR + ln] = acc[k];
    __syncthreads();
    {
        float* g_B2 = base + WS_B2;
        for (int t = tid; t < 4096; t += 256) g_B2[t] = B2l[(t>>6)*LSTR + (t&63)];
    }

    // D_SS = mask .* B2 -> P1
    for (int t = tid; t < 4096; t += 256) {
        int n = t >> 6, m = t & 63;
        float mv = (Ssh[n] == Ssh[m]) ? 1.f : actS[n]*actS[m];
        P1[n*LSTR + m] = mv * B2l[n*LSTR + m];
    }
    __syncthreads();

    // T2 = W^T * D_SS -> P2
    #pragma unroll
    for (int k = 0; k < 16; ++k) acc[k] = 0.f;
    for (int n = 0; n < 64; ++n) {
        float dv = P1[n*LSTR + ln];
        #pragma unroll
        for (int k = 0; k < 16; ++k) acc[k] += Wl[n*LSTR + (w*16 + k)] * dv;
    }
    #pragma unroll
    for (int k = 0; k < 16; ++k) P2[(w*16 + k)*LSTR + ln] = acc[k];
    __syncthreads();

    // C2 = T2 * W
    #pragma unroll
    for (int k = 0; k < 16; ++k) acc[k] = 0.f;
    for (int m = 0; m < 64; ++m) {
        float wv = Wl[m*LSTR + ln];
        #pragma unroll
        for (int k = 0; k < 16; ++k) acc[k] += P2[(w*16 + k)*LSTR + m] * wv;
    }
    {
        float* g_C2 = base + WS_C2;
        #pragma unroll
        for (int k = 0; k < 16; ++k) g_C2[(w*16 + k)*64 + ln] = acc[k];
    }
}

// ---------------------------------------------------------------------------
// k_out: grid (136, BATCH).
//  parts 0..127 : 4 non-S rows each; S-corrections computed LOCALLY from the
//                 A row (A symmetric) — no RA/RD global round trip.
//  parts 128..135: one 64-column chunk each; writes the s S-rows directly.
__global__ __launch_bounds__(256) void k_out(const float* __restrict__ A,
                                             const float* __restrict__ ws,
                                             float* __restrict__ out)
{
    const int part = blockIdx.x;
    const int b = blockIdx.y;
    const int tid = threadIdx.x;
    const float* base = ws + (size_t)b * WS_STRIDE;
    const int*   g_pm  = (const int*)(base + WS_PM);
    const int*   g_S   = (const int*)(base + WS_S);
    const float* g_act = base + WS_ACT;
    const float* g_W   = base + WS_W;
    const float* g_B2  = base + WS_B2;
    const float* g_C2  = base + WS_C2;
    const int scnt = ((const int*)(base + WS_SCNT))[0];
    const size_t seg = (size_t)BATCH*NDIM*NDIM;

    __shared__ float Wl[64*LSTR];          // 16.6 KB
    __shared__ float pool[2*64*LSTR];      // 33.3 KB (row: rowbuf|ArowS|ras|rds ; col: AS|RAt)
    __shared__ int   Ssh[64];
    __shared__ float actS[64];
    __shared__ int   pmj[64];
    __shared__ float actj[64];

    if (tid < 64) { int s = g_S[tid]; Ssh[tid] = s; actS[tid] = g_act[s]; }
    for (int t = tid; t < 1024; t += 256) {
        f4 w = ((const f4*)g_W)[t];
        int r = t >> 4, c = (t & 15) * 4;
        Wl[r*LSTR + c]   = w.x; Wl[r*LSTR + c+1] = w.y;
        Wl[r*LSTR + c+2] = w.z; Wl[r*LSTR + c+3] = w.w;
    }

    if (part < NDIM/4) {
        // ================= row path: 4 rows, one wave per row =================
        float* rowbuf = pool;              // [4][512]
        float* ArowS  = pool + 2048;       // [4][64]
        float* ras    = pool + 2048 + 256; // [4][64]
        float* rds    = pool + 2048 + 512; // [4][64]
        const int r = tid >> 6;            // row-within-block (== wave id)
        const int c = tid & 63;            // col-thread: cols 8c..8c+7
        const int i = part*4 + r;
        const int pi = g_pm[i];
        const float acti = g_act[i];
        const float* Arow = A + ((size_t)b*NDIM + i)*NDIM;

        f4 a0 = ((const f4*)Arow)[2*c];
        f4 a1 = ((const f4*)Arow)[2*c + 1];
        ((f4*)(rowbuf + r*512))[2*c]     = a0;
        ((f4*)(rowbuf + r*512))[2*c + 1] = a1;
        __syncthreads();

        // gather this row's S-column values
        ArowS[r*64 + c] = rowbuf[r*512 + Ssh[c]];
        __syncthreads();

        // ras[n] = sum_k W[n][k] * Arow[S[k]]   (thread = (r, n=c))
        {
            float acc = 0.f;
            #pragma unroll 8
            for (int k = 0; k < 64; ++k)
                acc += Wl[c*LSTR + k] * ArowS[r*64 + k];
            ras[r*64 + c] = acc;
        }
        __syncthreads();

        // rds[q] = acti * sum_n W[n][q] * actS[n] * ras[n]
        {
            float acc = 0.f;
            #pragma unroll 8
            for (int n = 0; n < 64; ++n)
                acc += Wl[n*LSTR + c] * (actS[n] * ras[r*64 + n]);
            rds[r*64 + c] = acc * acti;
        }
        __syncthreads();

        if (pi < 0) {
            int4   p0 = ((const int4*)g_pm)[2*c],  p1 = ((const int4*)g_pm)[2*c + 1];
            float4 q0 = ((const float4*)g_act)[2*c], q1 = ((const float4*)g_act)[2*c + 1];
            int   pm8[8] = {p0.x,p0.y,p0.z,p0.w, p1.x,p1.y,p1.z,p1.w};
            float aj8[8] = {q0.x,q0.y,q0.z,q0.w, q1.x,q1.y,q1.z,q1.w};
            float av8[8] = {a0.x,a0.y,a0.z,a0.w, a1.x,a1.y,a1.z,a1.w};
            float arec[8], dvv[8], rvv[8];
            const int j0 = 8*c;
            #pragma unroll
            for (int e = 0; e < 8; ++e) {
                int pj = pm8[e];
                int j = j0 + e;
                float a  = (pj >= 0) ? ras[r*64 + pj] : av8[e];
                float mv = (i == j) ? 1.f : acti * aj8[e];
                dvv[e]  = a * mv;
                arec[e] = (pj >= 0) ? rds[r*64 + pj] : dvv[e];
                rvv[e]  = (i == j) ? 1.f : 0.f;
            }
            const size_t ro = ((size_t)b*NDIM + i)*NDIM;
            f4 s0 = {arec[0],arec[1],arec[2],arec[3]};
            f4 s1 = {arec[4],arec[5],arec[6],arec[7]};
            f4 s2 = {rvv[0],rvv[1],rvv[2],rvv[3]};
            f4 s3 = {rvv[4],rvv[5],rvv[6],rvv[7]};
            f4 s4 = {dvv[0],dvv[1],dvv[2],dvv[3]};
            f4 s5 = {dvv[4],dvv[5],dvv[6],dvv[7]};
            __builtin_nontemporal_store(s0, (f4*)(out + ro) + 2*c);
            __builtin_nontemporal_store(s1, (f4*)(out + ro) + 2*c + 1);
            __builtin_nontemporal_store(s2, (f4*)(out + seg + ro) + 2*c);
            __builtin_nontemporal_store(s3, (f4*)(out + seg + ro) + 2*c + 1);
            __builtin_nontemporal_store(s4, (f4*)(out + 2*seg + ro) + 2*c);
            __builtin_nontemporal_store(s5, (f4*)(out + 2*seg + ro) + 2*c + 1);
        }
    } else {
        // ================= col path: 64 columns, writes s S-rows =================
        const int j0 = (part - NDIM/4) * 64;
        float* AS  = pool;                 // [64][64]
        float* RAt = pool + 4096;          // [64][64]
        if (tid < 64) { pmj[tid] = g_pm[j0 + tid]; actj[tid] = g_act[j0 + tid]; }
        __syncthreads();   // Ssh ready
        for (int t = tid; t < 1024; t += 256) {
            int n = t >> 4, cc = (t & 15) * 4;
            f4 v = ((const f4*)(A + ((size_t)b*NDIM + Ssh[n])*NDIM + j0))[t & 15];
            AS[n*64 + cc]   = v.x; AS[n*64 + cc+1] = v.y;
            AS[n*64 + cc+2] = v.z; AS[n*64 + cc+3] = v.w;
        }
        __syncthreads();

        const int g = tid >> 6;            // m-group: rows g*16..g*16+15
        const int j = tid & 63;
        float racc[16];

        // RA[m][j] = sum_n W[m][n] * AS[n][j]
        #pragma unroll
        for (int k = 0; k < 16; ++k) racc[k] = 0.f;
        for (int n = 0; n < 64; ++n) {
            float av = AS[n*64 + j];
            #pragma unroll
            for (int k = 0; k < 16; ++k) racc[k] += Wl[(g*16 + k)*LSTR + n] * av;
        }
        #pragma unroll
        for (int k = 0; k < 16; ++k) RAt[(g*16 + k)*64 + j] = racc[k];
        __syncthreads();

        // RD[m][j] = actj * sum_n W[n][m] * actS[n] * RAt[n][j]
        #pragma unroll
        for (int k = 0; k < 16; ++k) racc[k] = 0.f;
        for (int n = 0; n < 64; ++n) {
            float dt = actS[n] * RAt[n*64 + j];
            #pragma unroll
            for (int k = 0; k < 16; ++k) racc[k] += Wl[n*LSTR + g*16 + k] * dt;
        }

        const int   pjv = pmj[j];
        const float ajv = actj[j];
        #pragma unroll
        for (int k = 0; k < 16; ++k) {
            int m = g*16 + k;
            if (m >= scnt) continue;
            int Sm = Ssh[m];
            float rdv  = racc[k] * ajv;
            float arec = (pjv < 0) ? rdv : g_C2[m*64 + pjv];
            float afin = (pjv < 0) ? RAt[m*64 + j] : g_B2[m*64 + pjv];
            float mask = (Sm == j0 + j) ? 1.f : actS[m] * ajv;
            float dvv  = afin * mask;
            float rvv  = (pjv < 0) ? 0.f : Wl[m*LSTR + pjv];
            size_t ro = ((size_t)b*NDIM + Sm)*NDIM + j0 + j;
            __builtin_nontemporal_store(arec, out + ro);
            __builtin_nontemporal_store(rvv,  out + seg + ro);
            __builtin_nontemporal_store(dvv,  out + 2*seg + ro);
        }
    }
}

extern "C" void kernel_launch(void* const* d_in, const int* in_sizes, int n_in,
                              void* d_out, int out_size, void* d_ws, size_t ws_size,
                              hipStream_t stream) {
    const float* A       = (const float*)d_in[0];
    const float* O       = (const float*)d_in[1];
    const int*   indices = (const int*)d_in[2];
    const int*   wavelet = (const int*)d_in[3];
    float* ws  = (float*)d_ws;
    float* out = (float*)d_out;

    k_small<<<dim3(BATCH), 256, 0, stream>>>(A, O, indices, wavelet, ws);
    k_out  <<<dim3(NDIM/4 + 8, BATCH), 256, 0, stream>>>(A, ws, out);
}

// Round 8
// 187.575 us; speedup vs baseline: 1.1168x; 1.1168x over previous
//
#include <hip/hip_runtime.h>

#define BATCH 32
#define NDIM 512
#define LNUM 8
#define KDIM 8

// per-batch workspace layout (float offsets)
#define WS_PM     0        // int[512]  posmap: node -> pos in S, or -1
#define WS_S      512      // int[64]   S (padded with 0 beyond s)
#define WS_ACT    640      // float[512] active mask
#define WS_W      1152     // float[64*64]
#define WS_B2     5248     // float[64*64] B2 = W A_SS W^T
#define WS_C2     9344     // float[64*64] C2 = W^T D_SS W
#define WS_RA     13440    // float[64*512]  RA[m][j]
#define WS_RD     46208    // float[64*512]  RD[q][j]
#define WS_RAT    78976    // float[512*64]  RAT[j][m] = RA[m][j]
#define WS_RDT    111744   // float[512*64]  RDT[j][q] = RD[q][j]
#define WS_STRIDE 144512   // ~18.5 MB total for 32 batches

#define LSTR 65
typedef float f4 __attribute__((ext_vector_type(4)));

// ---------------------------------------------------------------------------
// k_small: per-batch serial chain (32 blocks): setup + W + B2/C2 to ws.
__global__ __launch_bounds__(256) void k_small(
    const float* __restrict__ A, const float* __restrict__ O,
    const int* __restrict__ indices, const int* __restrict__ wavelet,
    float* __restrict__ ws)
{
    const int b = blockIdx.x;
    const int tid = threadIdx.x;
    float* base = ws + (size_t)b * WS_STRIDE;

    __shared__ float Wl[64*LSTR];
    __shared__ float P1[64*LSTR];
    __shared__ float P2[64*LSTR];
    __shared__ float B2l[64*LSTR];
    __shared__ int   pml[NDIM];
    __shared__ float actl[NDIM];
    __shared__ float actS[64];
    __shared__ int   idxsh[64];
    __shared__ int   Ssh[64];
    __shared__ int   prow[KDIM];
    __shared__ float Oall[LNUM*KDIM*KDIM];
    __shared__ int   s_sh;

    for (int t = tid; t < LNUM*KDIM*KDIM; t += 256) {
        int l = t >> 6, k = t & 63;
        Oall[t] = O[((size_t)l*BATCH + b)*(KDIM*KDIM) + k];
    }
    if (tid < 64) idxsh[tid] = indices[b*64 + tid];
    for (int n = tid; n < NDIM; n += 256) { pml[n] = -1; actl[n] = 1.f; }
    __syncthreads();

    if (tid < 64) {
        int n = idxsh[tid];
        bool first = true;
        for (int t = 0; t < tid; ++t) if (idxsh[t] == n) first = false;
        unsigned long long m = __ballot(first);
        int rank = __popcll(m & ((1ull << tid) - 1ull));
        if (first) { pml[n] = rank; Ssh[rank] = n; }
        if (tid == 0) s_sh = (int)__popcll(m);
    }
    if (tid >= 64 && tid < 64 + LNUM) {
        actl[wavelet[b*LNUM + (tid - 64)]] = 0.f;
    }
    __syncthreads();
    const int s = s_sh;
    if (tid < 64 && tid >= s) Ssh[tid] = 0;
    __syncthreads();
    if (tid < 64) actS[tid] = actl[Ssh[tid]];

    {
        int*   g_posmap = (int*)(base + WS_PM);
        int*   g_S      = (int*)(base + WS_S);
        float* g_act    = base + WS_ACT;
        for (int n = tid; n < NDIM; n += 256) { g_posmap[n] = pml[n]; g_act[n] = actl[n]; }
        if (tid < 64) g_S[tid] = Ssh[tid];
    }

    // W build
    for (int t = tid; t < 4096; t += 256) {
        int rr = t >> 6, cc = t & 63;
        Wl[rr*LSTR + cc] = (rr == cc && rr < s) ? 1.f : 0.f;
    }
    __syncthreads();
    for (int l = 0; l < LNUM; ++l) {
        if (tid < KDIM) prow[tid] = pml[idxsh[l*KDIM + tid]];
        __syncthreads();
        for (int t = tid; t < KDIM*64; t += 256) {
            int i = t >> 6, c = t & 63;
            float acc = 0.f;
            #pragma unroll
            for (int j = 0; j < KDIM; ++j)
                acc += Oall[l*64 + i*KDIM + j] * Wl[prow[j]*LSTR + c];
            B2l[t] = acc;
        }
        __syncthreads();
        for (int t = tid; t < KDIM*64; t += 256) {
            int i = t >> 6, c = t & 63;
            Wl[prow[i]*LSTR + c] = B2l[t];
        }
        __syncthreads();
    }
    {
        float* g_W = base + WS_W;
        for (int t = tid; t < 4096; t += 256) g_W[t] = Wl[(t>>6)*LSTR + (t&63)];
    }

    // gather A_SS -> P1
    for (int t = tid; t < 4096; t += 256) {
        int n = t >> 6, m = t & 63;
        P1[n*LSTR + m] = A[((size_t)b*NDIM + Ssh[n])*NDIM + Ssh[m]];
    }
    __syncthreads();

    const int w = tid >> 6;
    const int ln = tid & 63;
    float acc[16];

    // T = W * A_SS -> P2
    #pragma unroll
    for (int k = 0; k < 16; ++k) acc[k] = 0.f;
    for (int n = 0; n < 64; ++n) {
        float as = P1[n*LSTR + ln];
        #pragma unroll
        for (int k = 0; k < 16; ++k) acc[k] += Wl[(w*16 + k)*LSTR + n] * as;
    }
    #pragma unroll
    for (int k = 0; k < 16; ++k) P2[(w*16 + k)*LSTR + ln] = acc[k];
    __syncthreads();

    // B2 = T * W^T
    #pragma unroll
    for (int k = 0; k < 16; ++k) acc[k] = 0.f;
    for (int m = 0; m < 64; ++m) {
        float wv = Wl[ln*LSTR + m];
        #pragma unroll
        for (int k = 0; k < 16; ++k) acc[k] += P2[(w*16 + k)*LSTR + m] * wv;
    }
    #pragma unroll
    for (int k = 0; k < 16; ++k) B2l[(w*16 + k)*LSTR + ln] = acc[k];
    __syncthreads();
    {
        float* g_B2 = base + WS_B2;
        for (int t = tid; t < 4096; t += 256) g_B2[t] = B2l[(t>>6)*LSTR + (t&63)];
    }

    // D_SS = mask .* B2 -> P1
    for (int t = tid; t < 4096; t += 256) {
        int n = t >> 6, m = t & 63;
        float mv = (Ssh[n] == Ssh[m]) ? 1.f : actS[n]*actS[m];
        P1[n*LSTR + m] = mv * B2l[n*LSTR + m];
    }
    __syncthreads();

    // T2 = W^T * D_SS -> P2
    #pragma unroll
    for (int k = 0; k < 16; ++k) acc[k] = 0.f;
    for (int n = 0; n < 64; ++n) {
        float dv = P1[n*LSTR + ln];
        #pragma unroll
        for (int k = 0; k < 16; ++k) acc[k] += Wl[n*LSTR + (w*16 + k)] * dv;
    }
    #pragma unroll
    for (int k = 0; k < 16; ++k) P2[(w*16 + k)*LSTR + ln] = acc[k];
    __syncthreads();

    // C2 = T2 * W
    #pragma unroll
    for (int k = 0; k < 16; ++k) acc[k] = 0.f;
    for (int m = 0; m < 64; ++m) {
        float wv = Wl[m*LSTR + ln];
        #pragma unroll
        for (int k = 0; k < 16; ++k) acc[k] += P2[(w*16 + k)*LSTR + m] * wv;
    }
    {
        float* g_C2 = base + WS_C2;
        #pragma unroll
        for (int k = 0; k < 16; ++k) g_C2[(w*16 + k)*64 + ln] = acc[k];
    }
}

// ---------------------------------------------------------------------------
// k_mid: grid (BATCH, 8) — 64-column chunks. Computes RA/RD and writes
// BOTH layouts: row-major (coalesced S-row reads in k_big) and transposed
// (L1-friendly per-row gathers in k_big).
__global__ __launch_bounds__(256) void k_mid(const float* __restrict__ A,
                                             float* __restrict__ ws)
{
    const int b = blockIdx.x;
    const int j0 = blockIdx.y * 64;
    const int tid = threadIdx.x;
    float* base = ws + (size_t)b * WS_STRIDE;
    const int*   g_S   = (const int*)(base + WS_S);
    const float* g_act = base + WS_ACT;
    const float* g_W   = base + WS_W;
    float* g_RA  = base + WS_RA;
    float* g_RD  = base + WS_RD;
    float* g_RAT = base + WS_RAT;
    float* g_RDT = base + WS_RDT;

    __shared__ float Wl[64*LSTR];
    __shared__ float AS[64*64];
    __shared__ float RAt[64*64];
    __shared__ int   Ssh[64];
    __shared__ float actS[64];
    __shared__ float actj[64];

    for (int t = tid; t < 1024; t += 256) {
        f4 w = ((const f4*)g_W)[t];
        int r = t >> 4, c = (t & 15) * 4;
        Wl[r*LSTR + c]   = w.x; Wl[r*LSTR + c+1] = w.y;
        Wl[r*LSTR + c+2] = w.z; Wl[r*LSTR + c+3] = w.w;
    }
    if (tid < 64) {
        int n = g_S[tid];
        Ssh[tid] = n;
        actS[tid] = g_act[n];
    }
    if (tid >= 64 && tid < 128) actj[tid-64] = g_act[j0 + (tid-64)];
    __syncthreads();

    // gather AS[n][c] = A[b][S[n]][j0+c] (f4 loads per row)
    for (int t = tid; t < 1024; t += 256) {
        int n = t >> 4, cc = (t & 15) * 4;
        f4 v = ((const f4*)(A + ((size_t)b*NDIM + Ssh[n])*NDIM + j0))[t & 15];
        AS[n*64 + cc]   = v.x; AS[n*64 + cc+1] = v.y;
        AS[n*64 + cc+2] = v.z; AS[n*64 + cc+3] = v.w;
    }
    __syncthreads();

    const int g = tid >> 6;            // rows g*16..g*16+15
    const int j = tid & 63;
    float racc[16];

    // RA[m][j] = sum_n W[m][n] * AS[n][j]
    #pragma unroll
    for (int k = 0; k < 16; ++k) racc[k] = 0.f;
    for (int n = 0; n < 64; ++n) {
        float av = AS[n*64 + j];
        #pragma unroll
        for (int k = 0; k < 16; ++k) racc[k] += Wl[(g*16 + k)*LSTR + n] * av;
    }
    #pragma unroll
    for (int k = 0; k < 16; ++k) {
        RAt[(g*16 + k)*64 + j] = racc[k];
        g_RA[(g*16 + k)*NDIM + j0 + j] = racc[k];
    }
    // transposed: 64B-contiguous per lane -> 4 f4 stores
    {
        f4* dst = (f4*)(g_RAT + (size_t)(j0 + j)*64 + g*16);
        #pragma unroll
        for (int q = 0; q < 4; ++q) {
            f4 v = { racc[4*q], racc[4*q+1], racc[4*q+2], racc[4*q+3] };
            dst[q] = v;
        }
    }
    __syncthreads();

    // RD[q][j] = actj * sum_n W[n][q] * actS[n] * RAt[n][j]
    // (valid for j not in S; S-columns/rows of RD/RDT are never consumed)
    #pragma unroll
    for (int k = 0; k < 16; ++k) racc[k] = 0.f;
    for (int n = 0; n < 64; ++n) {
        float dt = actS[n] * RAt[n*64 + j];
        #pragma unroll
        for (int k = 0; k < 16; ++k) racc[k] += Wl[n*LSTR + g*16 + k] * dt;
    }
    const float aj = actj[j];
    #pragma unroll
    for (int k = 0; k < 16; ++k) {
        float rd = racc[k] * aj;
        racc[k] = rd;
        g_RD[(g*16 + k)*NDIM + j0 + j] = rd;
    }
    {
        f4* dst = (f4*)(g_RDT + (size_t)(j0 + j)*64 + g*16);
        #pragma unroll
        for (int q = 0; q < 4; ++q) {
            f4 v = { racc[4*q], racc[4*q+1], racc[4*q+2], racc[4*q+3] };
            dst[q] = v;
        }
    }
}

// ---------------------------------------------------------------------------
// k_big: zero-LDS float4 pass over (b,i,j) writing A_rec, right, D.
// Gathers use transposed RAT/RDT rows (256 B, shared by the whole half-block).
__global__ __launch_bounds__(256) void k_big(const float* __restrict__ A,
                                             const float* __restrict__ ws,
                                             float* __restrict__ out)
{
    const int b = blockIdx.y;
    const int rh = threadIdx.x >> 7;          // 2 rows per block
    const int lane = threadIdx.x & 127;       // 128 float4s per row
    const int i = blockIdx.x*2 + rh;
    const int j0 = lane*4;

    const float* base = ws + (size_t)b * WS_STRIDE;
    const int*   posmap = (const int*)(base + WS_PM);
    const float* act = base + WS_ACT;
    const float* g_W  = base + WS_W;
    const float* g_B2 = base + WS_B2;
    const float* g_C2 = base + WS_C2;
    const float* RA  = base + WS_RA;
    const float* RD  = base + WS_RD;
    const float* RAT = base + WS_RAT;
    const float* RDT = base + WS_RDT;

    const int pi = posmap[i];
    const float acti = act[i];
    const size_t rowoff = ((size_t)b*NDIM + i)*NDIM;
    const size_t seg = (size_t)BATCH*NDIM*NDIM;

    int4   p4  = ((const int4*)posmap)[lane];
    float4 aj4 = ((const float4*)act)[lane];
    int   pm[4] = {p4.x, p4.y, p4.z, p4.w};
    float aj[4] = {aj4.x, aj4.y, aj4.z, aj4.w};

    float a[4], arec[4], dv[4], rv[4];

    if (pi < 0) {
        const float* rat = RAT + (size_t)i*64;   // 256 B, L1-hot per half-block
        const float* rdt = RDT + (size_t)i*64;
        float4 v = ((const float4*)(A + rowoff))[lane];
        a[0]=v.x; a[1]=v.y; a[2]=v.z; a[3]=v.w;
        #pragma unroll
        for (int c = 0; c < 4; ++c) {
            int pj = pm[c];
            if (pj >= 0) a[c] = rat[pj];
            float mv = (i == j0 + c) ? 1.f : acti * aj[c];
            dv[c] = a[c] * mv;
            arec[c] = (pj < 0) ? dv[c] : rdt[pj];
            rv[c] = (i == j0 + c) ? 1.f : 0.f;
        }
    } else {
        float4 v = ((const float4*)(RA + (size_t)pi*NDIM))[lane];
        float4 w = ((const float4*)(RD + (size_t)pi*NDIM))[lane];
        a[0]=v.x; a[1]=v.y; a[2]=v.z; a[3]=v.w;
        arec[0]=w.x; arec[1]=w.y; arec[2]=w.z; arec[3]=w.w;
        #pragma unroll
        for (int c = 0; c < 4; ++c) {
            int pj = pm[c];
            if (pj >= 0) {
                a[c]    = g_B2[pi*64 + pj];
                arec[c] = g_C2[pi*64 + pj];
                rv[c]   = g_W[pi*64 + pj];
            } else {
                rv[c] = 0.f;
            }
            float mv = (i == j0 + c) ? 1.f : acti * aj[c];
            dv[c] = a[c] * mv;
        }
    }

    ((float4*)(out + rowoff))[lane]         = make_float4(arec[0], arec[1], arec[2], arec[3]);
    ((float4*)(out + seg + rowoff))[lane]   = make_float4(rv[0], rv[1], rv[2], rv[3]);
    ((float4*)(out + 2*seg + rowoff))[lane] = make_float4(dv[0], dv[1], dv[2], dv[3]);
}

extern "C" void kernel_launch(void* const* d_in, const int* in_sizes, int n_in,
                              void* d_out, int out_size, void* d_ws, size_t ws_size,
                              hipStream_t stream) {
    const float* A       = (const float*)d_in[0];
    const float* O       = (const float*)d_in[1];
    const int*   indices = (const int*)d_in[2];
    const int*   wavelet = (const int*)d_in[3];
    float* ws  = (float*)d_ws;   // needs ~18.5 MB
    float* out = (float*)d_out;

    k_small<<<dim3(BATCH), 256, 0, stream>>>(A, O, indices, wavelet, ws);
    k_mid  <<<dim3(BATCH, 8), 256, 0, stream>>>(A, ws);
    k_big  <<<dim3(NDIM/2, BATCH), 256, 0, stream>>>(A, ws, out);
}